// Round 9
// baseline (437.396 us; speedup 1.0000x reference)
//
#include <hip/hip_runtime.h>

typedef __bf16 bf16x8 __attribute__((ext_vector_type(8)));
typedef __bf16 bf16x4 __attribute__((ext_vector_type(4)));
typedef __bf16 bf16x2 __attribute__((ext_vector_type(2)));
typedef float f32x4 __attribute__((ext_vector_type(4)));
typedef unsigned short u16;
typedef unsigned short u16x4 __attribute__((ext_vector_type(4)));
typedef unsigned short u16x8 __attribute__((ext_vector_type(8)));
typedef unsigned int u32;
typedef unsigned int u32x2 __attribute__((ext_vector_type(2)));
typedef unsigned int u32x4 __attribute__((ext_vector_type(4)));

__device__ __forceinline__ u16 f2bu(float f) {
  __bf16 h = (__bf16)f;
  return __builtin_bit_cast(u16, h);
}

// async global->LDS, 16B/lane. LDS dest = wave-uniform base + lane*16.
__device__ __forceinline__ void gld16(const u16* g, const __bf16* lds) {
  __builtin_amdgcn_global_load_lds(
      (const __attribute__((address_space(1))) u32*)(uintptr_t)g,
      (__attribute__((address_space(3))) u32*)(u32)(uintptr_t)lds, 16, 0, 0);
}

// ---------------- transpose tile helper: out_bf16[C][R] tile from in_f32[R][C] -------
__device__ __forceinline__ void tr_tile(const float* __restrict__ in, u16* __restrict__ out,
                                        int R, int C, int bx, int by, int tid) {
  __shared__ u16 t[64][65];
  int tx = tid & 63, ty = tid >> 6;
  int r0 = by * 64, c0 = bx * 64;
  for (int i = 0; i < 16; ++i)
    t[ty + i * 4][tx] = f2bu(in[(size_t)(r0 + ty + i * 4) * C + c0 + tx]);
  __syncthreads();
  for (int i = 0; i < 16; ++i)
    out[(size_t)(c0 + ty + i * 4) * R + r0 + tx] = t[tx][ty + i * 4];
}

// ---------------- fused prep: tr(Wqkv) [0,768) | tr(Wout) [768,1024) | cvt(x) [1024,3072)
__global__ __launch_bounds__(256) void prep(const float* __restrict__ Wqkv,
                                            u16* __restrict__ Wqkv_t,
                                            const float* __restrict__ Wout,
                                            u16* __restrict__ Wout_t,
                                            const float* __restrict__ x,
                                            u16* __restrict__ xb) {
  int id = blockIdx.x, tid = threadIdx.x;
  if (id < 768) {
    tr_tile(Wqkv, Wqkv_t, 1024, 3072, id % 48, id / 48, tid);
  } else if (id < 1024) {
    int id2 = id - 768;
    tr_tile(Wout, Wout_t, 1024, 1024, id2 % 16, id2 / 16, tid);
  } else {
    size_t i = ((size_t)(id - 1024) * 256 + tid) * 8;
    f32x4 a0 = *(const f32x4*)(x + i);
    f32x4 a1 = *(const f32x4*)(x + i + 4);
    bf16x8 v;
    for (int j = 0; j < 4; ++j) { v[j] = (__bf16)a0[j]; v[j + 4] = (__bf16)a1[j]; }
    *(bf16x8*)(xb + i) = v;
  }
}

// ---------------- GEMM: dbuf K-loop, ONE barrier per 32-k step, XCD-swizzled --------
// MODE 0: C f32 -> O0.
// MODE 1: qkv scatter. Q(O0) scaled by 0.125*log2(e), [b,h,s,d]. K(O1) [b,h,s,d].
// V(O2) TRANSPOSED [b,h,d,s]. Epilogues coalesced via LDS restage (Q/K) and
// in-register permlane transpose (V).
template <int MODE, int TM, int TN, int MT, int NT, int XM, int XN>
__global__ __launch_bounds__(256) void gemm_bt(const u16* __restrict__ A,
                                               const u16* __restrict__ Bt,
                                               const float* __restrict__ bias,
                                               void* __restrict__ O0v,
                                               u16* __restrict__ O1,
                                               u16* __restrict__ O2,
                                               int M, int N, int K) {
  constexpr int NI = TM / 32;
  constexpr int NJ = TN / 32;
  constexpr int AE = TM * 32;
  constexpr int BE = TN * 32;
  __shared__ __bf16 smem[2 * (AE + BE)];

  int tid = threadIdx.x;
  int w = tid >> 6, lane = tid & 63, quad = lane >> 4, l16 = lane & 15;
  int wr = w >> 1, wc = w & 1;

  // XCD swizzle: xcd = id%8 owns tiles [mg*XM, mg*XM+XM) x [ng*XN, ng*XN+XN)
  int id = blockIdx.x;
  int xcd = id & 7, s0i = id >> 3;
  int mg = xcd % (MT / XM), ng = xcd / (MT / XM);
  int sm = s0i % XM, sn = s0i / XM;
  int m0 = (mg * XM + sm) * TM, n0 = (ng * XN + sn) * TN;

  int srow = w * 16 + (lane >> 2);
  int sch = (lane & 3) ^ ((lane >> 3) & 3);
  const u16* Ag = A + (size_t)(m0 + srow) * K + sch * 8;
  const u16* Bg = Bt + (size_t)(n0 + srow) * K + sch * 8;

  int swl = (quad ^ ((l16 >> 1) & 3)) << 3;

  f32x4 acc[NI][NJ] = {};

#define GLD_STEP(c, kk)                                                          \
  {                                                                              \
    for (int p = 0; p < TM / 64; ++p)                                            \
      gld16(Ag + (size_t)p * 64 * K + (kk), smem + (c) * (AE + BE) + w * 512 + p * 2048); \
    for (int p = 0; p < TN / 64; ++p)                                            \
      gld16(Bg + (size_t)p * 64 * K + (kk), smem + (c) * (AE + BE) + AE + w * 512 + p * 2048); \
  }

  GLD_STEP(0, 0);
  int NS = K / 32;
  for (int s = 0; s < NS; ++s) {
    int cur = s & 1;
    __syncthreads();  // drains step-s loads (issued one compute-phase ago)
    if (s + 1 < NS) GLD_STEP(1 - cur, (s + 1) * 32);
    const __bf16* Asub = smem + cur * (AE + BE);
    const __bf16* Bsub = Asub + AE;
    bf16x8 af[NI], bfr[NJ];
    for (int i = 0; i < NI; ++i)
      af[i] = *(const bf16x8*)(Asub + (wr * (TM / 2) + i * 16 + l16) * 32 + swl);
    for (int j = 0; j < NJ; ++j)
      bfr[j] = *(const bf16x8*)(Bsub + (wc * (TN / 2) + j * 16 + l16) * 32 + swl);
    for (int i = 0; i < NI; ++i)
      for (int j = 0; j < NJ; ++j)
        acc[i][j] = __builtin_amdgcn_mfma_f32_16x16x32_bf16(af[i], bfr[j], acc[i][j], 0, 0, 0);
  }
#undef GLD_STEP

  if (MODE == 0) {
    float* O0 = (float*)O0v;
    for (int j = 0; j < NJ; ++j) {
      int n = n0 + wc * (TN / 2) + j * 16 + l16;
      float bv = bias[n];
      for (int i = 0; i < NI; ++i) {
        int mb = m0 + wr * (TM / 2) + i * 16 + quad * 4;
        for (int r = 0; r < 4; ++r)
          O0[(size_t)(mb + r) * N + n] = acc[i][j][r] + bv;
      }
    }
  } else {
    constexpr float QSC = 0.125f * 1.44269504f;  // softmax scale * log2(e) folded into Q
    int bw = n0 >> 10;  // block-uniform: TN=128 divides 1024
    if (bw < 2) {
      // ---- Q/K tile: LDS restage -> fully coalesced 128B head-row stores ----
      u16* Od = bw ? O1 : (u16*)O0v;
      float sc = bw ? 1.f : QSC;
      __syncthreads();  // staging smem dead after final K-step reads
      u16* Ls = (u16*)smem;  // logical [row 0..TM) x [col 0..TN), granule-XOR'd
      for (int j = 0; j < NJ; ++j) {
        int col = wc * (TN / 2) + j * 16 + l16;
        float bv = bias[n0 + col];
        for (int i = 0; i < NI; ++i) {
          int rowb = wr * (TM / 2) + i * 16 + quad * 4;
          for (int r = 0; r < 4; ++r) {
            int row = rowb + r;
            Ls[(size_t)row * TN + (col ^ ((row & 7) << 4))] = f2bu((acc[i][j][r] + bv) * sc);
          }
        }
      }
      __syncthreads();
      for (int k = 0; k < TM * TN / 8 / 256; ++k) {
        int ch = tid + k * 256;
        int row = ch >> 4, col0 = (ch & 15) * 8;
        u16x8 v8 = *(const u16x8*)(Ls + (size_t)row * TN + (col0 ^ ((row & 7) << 4)));
        int m = m0 + row;
        int b = m >> 11, s = m & 2047;
        int n = n0 + col0;
        int h = (n & 1023) >> 6, d0 = n & 63;
        // 8 consecutive lanes cover one full 128B row [b,h,s,0..63]
        *(u16x8*)(Od + (((size_t)(b * 16 + h)) * 2048 + s) * 64 + d0) = v8;
      }
    } else {
      // ---- V tile: in-register permlane transpose -> u16x8 stores (8 consec s) ----
      for (int j = 0; j < NJ; ++j) {
        int n = n0 + wc * (TN / 2) + j * 16 + l16;
        int h = (n & 1023) >> 6, d = n & 63;
        float bv = bias[n];
        for (int pr = 0; pr < NI / 2; ++pr) {
          const f32x4& e = acc[2 * pr][j];
          const f32x4& f = acc[2 * pr + 1][j];
          bf16x2 e01 = {(__bf16)(e[0] + bv), (__bf16)(e[1] + bv)};
          bf16x2 e23 = {(__bf16)(e[2] + bv), (__bf16)(e[3] + bv)};
          bf16x2 f01 = {(__bf16)(f[0] + bv), (__bf16)(f[1] + bv)};
          bf16x2 f23 = {(__bf16)(f[2] + bv), (__bf16)(f[3] + bv)};
          u32 E[2] = {__builtin_bit_cast(u32, e01), __builtin_bit_cast(u32, e23)};
          u32 F[2] = {__builtin_bit_cast(u32, f01), __builtin_bit_cast(u32, f23)};
          u32 G[2], H[2];
          for (int w2 = 0; w2 < 2; ++w2) {
            u32x2 s1 = __builtin_amdgcn_permlane32_swap(E[w2], F[w2], false, false);
            u32x2 s2 = __builtin_amdgcn_permlane16_swap(s1[0], s1[1], false, false);
            G[w2] = s2[0];
            H[w2] = s2[1];
          }
          u32x4 pk = {G[0], G[1], H[0], H[1]};  // 8 consecutive m for this lane's col
          int m = m0 + wr * (TM / 2) + pr * 32 + quad * 8;
          int b = m >> 11, s = m & 2047;
          *(u32x4*)(O2 + (((size_t)(b * 16 + h)) * 64 + d) * 2048 + s) = pk;
        }
      }
    }
  }
}

// ---------------- flash attention: 4-way split-KV, 1024 threads, 8 waves/SIMD -------
// R9: R8 showed 4 waves/SIMD with no pipe >46% (VALU 45, MFMA 35) -> still
// latency-limited; VGPR=52 leaves occupancy headroom. 4 KV-groups x 4 waves,
// group g covers t in [g*512, (g+1)*512) in KVB=32 tiles (16 iters, same barrier
// count as R8). Per-group LDS K[2][32x64] + V[2][64x32-transposed] = 16KB;
// block total 64KB -> 2 blocks/CU = 32 waves/CU. Per-wave iter: QK 8 MFMA,
// single permlane stage (pfA/pfB cover t0..31), lsum 2, PV 8 (V-granule swizzle
// re-derived for 32-wide rows: store pos = g^((row>>1)&3), read quad^((l16>>1)&3)
// -> 2-way bank alias = free). Merge: 3 LDS phases (1->0, 3->2 in two 21-stride
// chunks; 2->0 at 41-stride) in the dead 64KB.
__global__ __launch_bounds__(1024, 8) void flash_attn(const u16* __restrict__ Q,
                                                      const u16* __restrict__ K,
                                                      const u16* __restrict__ Vt,
                                                      u16* __restrict__ AO) {
  constexpr int S = 2048;
  constexpr int QTR = S / 4;      // 512 kv per group
  constexpr int KVB = 32;         // t-tile per iter
  constexpr int NIT = QTR / KVB;  // 16
  __shared__ __bf16 lds[4][2][2][KVB * 64];  // [grp][K|V][dbuf][2048] = 64KB

  int bh = blockIdx.x, qbase = blockIdx.y * 128;
  int tid = threadIdx.x;
  int grp = tid >> 8, gtid = tid & 255;
  int w = gtid >> 6, lane = tid & 63, quad = lane >> 4, l16 = lane & 15;

  const u16* Qh = Q + (size_t)bh * S * 64;
  const u16* Kh = K + (size_t)bh * S * 64 + (size_t)grp * QTR * 64;
  const u16* Vh = Vt + (size_t)bh * 64 * S + grp * QTR;  // Vt[d][s], col offset

  // two q-row groups per wave: A = w*32 + l16, B = A + 16 (same rows in all grps)
  int qrowA = qbase + w * 32 + l16;
  int qrowB = qrowA + 16;
  bf16x8 qf0a = *(const bf16x8*)(Qh + (size_t)qrowA * 64 + quad * 8);
  bf16x8 qf1a = *(const bf16x8*)(Qh + (size_t)qrowA * 64 + 32 + quad * 8);
  bf16x8 qf0b = *(const bf16x8*)(Qh + (size_t)qrowB * 64 + quad * 8);
  bf16x8 qf1b = *(const bf16x8*)(Qh + (size_t)qrowB * 64 + 32 + quad * 8);

  bf16x8 vone;
#pragma unroll
  for (int j = 0; j < 8; ++j) vone[j] = (__bf16)1.0f;

  // staging: 2 gld16/thread/iter, pre-swizzled global source, linear LDS dest.
  // K: wave w stages t-rows [8w,8w+8) (rows of 64 bf16, 8 granules, XOR row&7).
  // V: wave w stages d-rows [16w,16w+16) (rows of 32 bf16, 4 granules, XOR (row>>1)&3).
  int lrK = lane >> 3;
  const u16* Ksrc = Kh + ((size_t)(w * 8 + lrK)) * 64 + (((lane & 7) ^ lrK) << 3);
  int lrV = lane >> 2;
  const u16* Vsrc = Vh + ((size_t)(w * 16 + lrV)) * S + (((lane & 3) ^ ((lane >> 3) & 3)) << 3);
  const __bf16* Kdst = &lds[grp][0][0][0] + w * 512;
  const __bf16* Vdst = &lds[grp][1][0][0] + w * 512;

#define STAGE(c, tb)                                     \
  {                                                      \
    gld16(Ksrc + (size_t)(tb) * 64, Kdst + (c) * 2048);  \
    gld16(Vsrc + (tb), Vdst + (c) * 2048);               \
  }

  STAGE(0, 0);
  __syncthreads();

  f32x4 oA[4] = {};
  f32x4 oB[4] = {};
  f32x4 lfA = {};
  f32x4 lfB = {};
  int xr = l16 & 7;
  int xv = (l16 >> 1) & 3;
  const __bf16* Kb0 = &lds[grp][0][0][0];
  const __bf16* Vb0 = &lds[grp][1][0][0];

  for (int it = 0; it < NIT; ++it) {
    int c = it & 1;
    if (it + 1 < NIT) STAGE(1 - c, (it + 1) * KVB);

    // QK^T + exp2, packed into u32 words (compiler fuses to v_cvt_pk_bf16_f32)
    u32 pwA[2][2], pwB[2][2];
#pragma unroll
    for (int nt = 0; nt < 2; ++nt) {
      const __bf16* kb = Kb0 + c * 2048 + (nt * 16 + l16) * 64;
      bf16x8 kf0 = *(const bf16x8*)(kb + ((quad ^ xr) << 3));
      bf16x8 kf1 = *(const bf16x8*)(kb + (((quad + 4) ^ xr) << 3));
      f32x4 ca = {0.f, 0.f, 0.f, 0.f};
      f32x4 cb = {0.f, 0.f, 0.f, 0.f};
      __builtin_amdgcn_s_setprio(1);
      ca = __builtin_amdgcn_mfma_f32_16x16x32_bf16(kf0, qf0a, ca, 0, 0, 0);
      cb = __builtin_amdgcn_mfma_f32_16x16x32_bf16(kf0, qf0b, cb, 0, 0, 0);
      ca = __builtin_amdgcn_mfma_f32_16x16x32_bf16(kf1, qf1a, ca, 0, 0, 0);
      cb = __builtin_amdgcn_mfma_f32_16x16x32_bf16(kf1, qf1b, cb, 0, 0, 0);
      __builtin_amdgcn_s_setprio(0);
      bf16x2 a01 = {(__bf16)__builtin_amdgcn_exp2f(ca[0]), (__bf16)__builtin_amdgcn_exp2f(ca[1])};
      bf16x2 a23 = {(__bf16)__builtin_amdgcn_exp2f(ca[2]), (__bf16)__builtin_amdgcn_exp2f(ca[3])};
      bf16x2 b01 = {(__bf16)__builtin_amdgcn_exp2f(cb[0]), (__bf16)__builtin_amdgcn_exp2f(cb[1])};
      bf16x2 b23 = {(__bf16)__builtin_amdgcn_exp2f(cb[2]), (__bf16)__builtin_amdgcn_exp2f(cb[3])};
      pwA[nt][0] = __builtin_bit_cast(u32, a01);
      pwA[nt][1] = __builtin_bit_cast(u32, a23);
      pwB[nt][0] = __builtin_bit_cast(u32, b01);
      pwB[nt][1] = __builtin_bit_cast(u32, b23);
    }

    // register-only redistribution (single stage: nt0/nt1 -> pf covering t0..31)
    bf16x8 pfA, pfB;
    {
      u32 GA[2], HA[2], GB[2], HB[2];
#pragma unroll
      for (int w2 = 0; w2 < 2; ++w2) {
        u32x2 s1a = __builtin_amdgcn_permlane32_swap(pwA[0][w2], pwA[1][w2], false, false);
        u32x2 s2a = __builtin_amdgcn_permlane16_swap(s1a[0], s1a[1], false, false);
        GA[w2] = s2a[0];
        HA[w2] = s2a[1];
        u32x2 s1b = __builtin_amdgcn_permlane32_swap(pwB[0][w2], pwB[1][w2], false, false);
        u32x2 s2b = __builtin_amdgcn_permlane16_swap(s1b[0], s1b[1], false, false);
        GB[w2] = s2b[0];
        HB[w2] = s2b[1];
      }
      u32x4 pa = {GA[0], GA[1], HA[0], HA[1]};
      u32x4 pb = {GB[0], GB[1], HB[0], HB[1]};
      pfA = __builtin_bit_cast(bf16x8, pa);
      pfB = __builtin_bit_cast(bf16x8, pb);
    }

    // l = row-sums of P via matrix pipe (B = ones); C-layout row matches o's row.
    __builtin_amdgcn_s_setprio(1);
    lfA = __builtin_amdgcn_mfma_f32_16x16x32_bf16(pfA, vone, lfA, 0, 0, 0);
    lfB = __builtin_amdgcn_mfma_f32_16x16x32_bf16(pfB, vone, lfB, 0, 0, 0);
    __builtin_amdgcn_s_setprio(0);

#pragma unroll
    for (int dt = 0; dt < 4; ++dt) {
      const __bf16* vb = Vb0 + c * 2048 + (dt * 16 + l16) * 32;
      bf16x8 v0 = *(const bf16x8*)(vb + ((quad ^ xv) << 3));
      __builtin_amdgcn_s_setprio(1);
      oA[dt] = __builtin_amdgcn_mfma_f32_16x16x32_bf16(pfA, v0, oA[dt], 0, 0, 0);
      oB[dt] = __builtin_amdgcn_mfma_f32_16x16x32_bf16(pfB, v0, oB[dt], 0, 0, 0);
      __builtin_amdgcn_s_setprio(0);
    }
    __syncthreads();  // drains this iter's STAGE loads; all groups same iter count
  }
#undef STAGE

  // ---- 4-way split-KV merge through dead LDS. Odd strides (21/41 f32) -> no
  // bank conflicts. Phase 1/2: grp1->grp0, grp3->grp2 (oA+lfA, then oB+lfB).
  // Phase 3: grp2->grp0 (all 40). grp0 normalizes and writes.
  float* mf = (float*)&lds[0][0][0][0];
  if (grp & 1) {
    float* p = mf + (size_t)((grp >> 1) * 256 + gtid) * 21;
#pragma unroll
    for (int dt = 0; dt < 4; ++dt)
#pragma unroll
      for (int r = 0; r < 4; ++r) p[dt * 4 + r] = oA[dt][r];
#pragma unroll
    for (int r = 0; r < 4; ++r) p[16 + r] = lfA[r];
  }
  __syncthreads();
  if (!(grp & 1)) {
    const float* p = mf + (size_t)((grp >> 1) * 256 + gtid) * 21;
#pragma unroll
    for (int dt = 0; dt < 4; ++dt)
#pragma unroll
      for (int r = 0; r < 4; ++r) oA[dt][r] += p[dt * 4 + r];
#pragma unroll
    for (int r = 0; r < 4; ++r) lfA[r] += p[16 + r];
  }
  __syncthreads();
  if (grp & 1) {
    float* p = mf + (size_t)((grp >> 1) * 256 + gtid) * 21;
#pragma unroll
    for (int dt = 0; dt < 4; ++dt)
#pragma unroll
      for (int r = 0; r < 4; ++r) p[dt * 4 + r] = oB[dt][r];
#pragma unroll
    for (int r = 0; r < 4; ++r) p[16 + r] = lfB[r];
  }
  __syncthreads();
  if (!(grp & 1)) {
    const float* p = mf + (size_t)((grp >> 1) * 256 + gtid) * 21;
#pragma unroll
    for (int dt = 0; dt < 4; ++dt)
#pragma unroll
      for (int r = 0; r < 4; ++r) oB[dt][r] += p[dt * 4 + r];
#pragma unroll
    for (int r = 0; r < 4; ++r) lfB[r] += p[16 + r];
  }
  __syncthreads();
  if (grp == 2) {
    float* p = mf + (size_t)gtid * 41;
#pragma unroll
    for (int dt = 0; dt < 4; ++dt)
#pragma unroll
      for (int r = 0; r < 4; ++r) {
        p[dt * 4 + r] = oA[dt][r];
        p[16 + dt * 4 + r] = oB[dt][r];
      }
#pragma unroll
    for (int r = 0; r < 4; ++r) {
      p[32 + r] = lfA[r];
      p[36 + r] = lfB[r];
    }
  }
  __syncthreads();
  if (grp == 0) {
    const float* p = mf + (size_t)gtid * 41;
    float linvA[4], linvB[4];
#pragma unroll
    for (int r = 0; r < 4; ++r) {
      linvA[r] = 1.f / (lfA[r] + p[32 + r]);
      linvB[r] = 1.f / (lfB[r] + p[36 + r]);
    }
    int b = bh >> 4, h = bh & 15;
    for (int dt = 0; dt < 4; ++dt)
      for (int r = 0; r < 4; ++r) {
        int sA = qbase + w * 32 + quad * 4 + r;
        int sB = sA + 16;
        int d = dt * 16 + l16;
        AO[(((size_t)b * 2048 + sA) * 16 + h) * 64 + d] = f2bu((oA[dt][r] + p[dt * 4 + r]) * linvA[r]);
        AO[(((size_t)b * 2048 + sB) * 16 + h) * 64 + d] = f2bu((oB[dt][r] + p[16 + dt * 4 + r]) * linvB[r]);
      }
  }
}

// ---------------- launch ----------------
extern "C" void kernel_launch(void* const* d_in, const int* in_sizes, int n_in,
                              void* d_out, int out_size, void* d_ws, size_t ws_size,
                              hipStream_t stream) {
  const float* x    = (const float*)d_in[0];  // [4096,1024] f32
  const float* Wqkv = (const float*)d_in[1];  // [1024,3072] f32
  const float* bqkv = (const float*)d_in[2];  // [3072] f32
  const float* Wout = (const float*)d_in[3];  // [1024,1024] f32
  const float* bout = (const float*)d_in[4];  // [1024] f32
  float* out = (float*)d_out;                 // [4096,1024] f32

  u16* ws = (u16*)d_ws;
  size_t off = 0;
  u16* Wqkv_t = ws + off; off += (size_t)3072 * 1024;
  u16* Wout_t = ws + off; off += (size_t)1024 * 1024;
  u16* xb     = ws + off; off += (size_t)4096 * 1024;  // AO aliases xb (dead after gemm1)
  u16* Qb     = ws + off; off += (size_t)32 * 2048 * 64;
  u16* Kb     = ws + off; off += (size_t)32 * 2048 * 64;
  u16* Vtb    = ws + off; off += (size_t)32 * 2048 * 64;  // written TRANSPOSED by gemm1
  u16* AO     = xb;
  // total: ~42 MB

  prep<<<dim3(3072), 256, 0, stream>>>(Wqkv, Wqkv_t, Wout, Wout_t, x, xb);
  // gemm1: 32 m-tiles x 24 n-tiles (TM=TN=128); XCD region 8m x 12n (A 2MB + Bt 3MB / L2)
  gemm_bt<1, 128, 128, 32, 24, 8, 12><<<dim3(768), 256, 0, stream>>>(
      xb, Wqkv_t, bqkv, (void*)Qb, Kb, Vtb, 4096, 3072, 1024);
  // flash: 128 q-rows per block, 1024 threads (4 KV-quarter groups x 4 waves);
  // blockIdx.x fastest -> all q-blocks of head bh land on XCD bh%8 (4 heads x
  // 512KB K+V = 2MB per L2). 512 blocks, 2/CU, 8 waves/SIMD.
  flash_attn<<<dim3(32, 16), 1024, 0, stream>>>(Qb, Kb, Vtb, AO);
  // gemm2: 32 m-tiles x 16 n-tiles (TM=128, TN=64); XCD region 8m x 8n (A 2MB + Bt 1MB / L2)
  gemm_bt<0, 128, 64, 32, 16, 8, 8><<<dim3(512), 256, 0, stream>>>(
      AO, Wout_t, bout, (void*)out, nullptr, nullptr, 4096, 1024, 1024);
}

// Round 10
// 178.795 us; speedup vs baseline: 2.4464x; 2.4464x over previous
//
#include <hip/hip_runtime.h>

typedef __bf16 bf16x8 __attribute__((ext_vector_type(8)));
typedef __bf16 bf16x4 __attribute__((ext_vector_type(4)));
typedef __bf16 bf16x2 __attribute__((ext_vector_type(2)));
typedef float f32x4 __attribute__((ext_vector_type(4)));
typedef unsigned short u16;
typedef unsigned short u16x4 __attribute__((ext_vector_type(4)));
typedef unsigned short u16x8 __attribute__((ext_vector_type(8)));
typedef unsigned int u32;
typedef unsigned int u32x2 __attribute__((ext_vector_type(2)));
typedef unsigned int u32x4 __attribute__((ext_vector_type(4)));

__device__ __forceinline__ u16 f2bu(float f) {
  __bf16 h = (__bf16)f;
  return __builtin_bit_cast(u16, h);
}

// async global->LDS, 16B/lane. LDS dest = wave-uniform base + lane*16.
__device__ __forceinline__ void gld16(const u16* g, const __bf16* lds) {
  __builtin_amdgcn_global_load_lds(
      (const __attribute__((address_space(1))) u32*)(uintptr_t)g,
      (__attribute__((address_space(3))) u32*)(u32)(uintptr_t)lds, 16, 0, 0);
}

// ---------------- transpose tile helper: out_bf16[C][R] tile from in_f32[R][C] -------
__device__ __forceinline__ void tr_tile(const float* __restrict__ in, u16* __restrict__ out,
                                        int R, int C, int bx, int by, int tid) {
  __shared__ u16 t[64][65];
  int tx = tid & 63, ty = tid >> 6;
  int r0 = by * 64, c0 = bx * 64;
  for (int i = 0; i < 16; ++i)
    t[ty + i * 4][tx] = f2bu(in[(size_t)(r0 + ty + i * 4) * C + c0 + tx]);
  __syncthreads();
  for (int i = 0; i < 16; ++i)
    out[(size_t)(c0 + ty + i * 4) * R + r0 + tx] = t[tx][ty + i * 4];
}

// ---------------- fused prep: tr(Wqkv) [0,768) | tr(Wout) [768,1024) | cvt(x) [1024,3072)
__global__ __launch_bounds__(256) void prep(const float* __restrict__ Wqkv,
                                            u16* __restrict__ Wqkv_t,
                                            const float* __restrict__ Wout,
                                            u16* __restrict__ Wout_t,
                                            const float* __restrict__ x,
                                            u16* __restrict__ xb) {
  int id = blockIdx.x, tid = threadIdx.x;
  if (id < 768) {
    tr_tile(Wqkv, Wqkv_t, 1024, 3072, id % 48, id / 48, tid);
  } else if (id < 1024) {
    int id2 = id - 768;
    tr_tile(Wout, Wout_t, 1024, 1024, id2 % 16, id2 / 16, tid);
  } else {
    size_t i = ((size_t)(id - 1024) * 256 + tid) * 8;
    f32x4 a0 = *(const f32x4*)(x + i);
    f32x4 a1 = *(const f32x4*)(x + i + 4);
    bf16x8 v;
    for (int j = 0; j < 4; ++j) { v[j] = (__bf16)a0[j]; v[j + 4] = (__bf16)a1[j]; }
    *(bf16x8*)(xb + i) = v;
  }
}

// ---------------- GEMM: dbuf K-loop, ONE barrier per 32-k step, XCD-swizzled --------
// MODE 0: C f32 -> O0.
// MODE 1: qkv scatter. Q(O0) scaled by 0.125*log2(e), [b,h,s,d]. K(O1) [b,h,s,d].
// V(O2) TRANSPOSED [b,h,d,s]. Epilogues coalesced via LDS restage (Q/K) and
// in-register permlane transpose (V).
template <int MODE, int TM, int TN, int MT, int NT, int XM, int XN>
__global__ __launch_bounds__(256) void gemm_bt(const u16* __restrict__ A,
                                               const u16* __restrict__ Bt,
                                               const float* __restrict__ bias,
                                               void* __restrict__ O0v,
                                               u16* __restrict__ O1,
                                               u16* __restrict__ O2,
                                               int M, int N, int K) {
  constexpr int NI = TM / 32;
  constexpr int NJ = TN / 32;
  constexpr int AE = TM * 32;
  constexpr int BE = TN * 32;
  __shared__ __bf16 smem[2 * (AE + BE)];

  int tid = threadIdx.x;
  int w = tid >> 6, lane = tid & 63, quad = lane >> 4, l16 = lane & 15;
  int wr = w >> 1, wc = w & 1;

  // XCD swizzle: xcd = id%8 owns tiles [mg*XM, mg*XM+XM) x [ng*XN, ng*XN+XN)
  int id = blockIdx.x;
  int xcd = id & 7, s0i = id >> 3;
  int mg = xcd % (MT / XM), ng = xcd / (MT / XM);
  int sm = s0i % XM, sn = s0i / XM;
  int m0 = (mg * XM + sm) * TM, n0 = (ng * XN + sn) * TN;

  int srow = w * 16 + (lane >> 2);
  int sch = (lane & 3) ^ ((lane >> 3) & 3);
  const u16* Ag = A + (size_t)(m0 + srow) * K + sch * 8;
  const u16* Bg = Bt + (size_t)(n0 + srow) * K + sch * 8;

  int swl = (quad ^ ((l16 >> 1) & 3)) << 3;

  f32x4 acc[NI][NJ] = {};

#define GLD_STEP(c, kk)                                                          \
  {                                                                              \
    for (int p = 0; p < TM / 64; ++p)                                            \
      gld16(Ag + (size_t)p * 64 * K + (kk), smem + (c) * (AE + BE) + w * 512 + p * 2048); \
    for (int p = 0; p < TN / 64; ++p)                                            \
      gld16(Bg + (size_t)p * 64 * K + (kk), smem + (c) * (AE + BE) + AE + w * 512 + p * 2048); \
  }

  GLD_STEP(0, 0);
  int NS = K / 32;
  for (int s = 0; s < NS; ++s) {
    int cur = s & 1;
    __syncthreads();  // drains step-s loads (issued one compute-phase ago)
    if (s + 1 < NS) GLD_STEP(1 - cur, (s + 1) * 32);
    const __bf16* Asub = smem + cur * (AE + BE);
    const __bf16* Bsub = Asub + AE;
    bf16x8 af[NI], bfr[NJ];
    for (int i = 0; i < NI; ++i)
      af[i] = *(const bf16x8*)(Asub + (wr * (TM / 2) + i * 16 + l16) * 32 + swl);
    for (int j = 0; j < NJ; ++j)
      bfr[j] = *(const bf16x8*)(Bsub + (wc * (TN / 2) + j * 16 + l16) * 32 + swl);
    for (int i = 0; i < NI; ++i)
      for (int j = 0; j < NJ; ++j)
        acc[i][j] = __builtin_amdgcn_mfma_f32_16x16x32_bf16(af[i], bfr[j], acc[i][j], 0, 0, 0);
  }
#undef GLD_STEP

  if (MODE == 0) {
    float* O0 = (float*)O0v;
    for (int j = 0; j < NJ; ++j) {
      int n = n0 + wc * (TN / 2) + j * 16 + l16;
      float bv = bias[n];
      for (int i = 0; i < NI; ++i) {
        int mb = m0 + wr * (TM / 2) + i * 16 + quad * 4;
        for (int r = 0; r < 4; ++r)
          O0[(size_t)(mb + r) * N + n] = acc[i][j][r] + bv;
      }
    }
  } else {
    constexpr float QSC = 0.125f * 1.44269504f;  // softmax scale * log2(e) folded into Q
    int bw = n0 >> 10;  // block-uniform: TN=128 divides 1024
    if (bw < 2) {
      // ---- Q/K tile: LDS restage -> fully coalesced 128B head-row stores ----
      u16* Od = bw ? O1 : (u16*)O0v;
      float sc = bw ? 1.f : QSC;
      __syncthreads();  // staging smem dead after final K-step reads
      u16* Ls = (u16*)smem;  // logical [row 0..TM) x [col 0..TN), granule-XOR'd
      for (int j = 0; j < NJ; ++j) {
        int col = wc * (TN / 2) + j * 16 + l16;
        float bv = bias[n0 + col];
        for (int i = 0; i < NI; ++i) {
          int rowb = wr * (TM / 2) + i * 16 + quad * 4;
          for (int r = 0; r < 4; ++r) {
            int row = rowb + r;
            Ls[(size_t)row * TN + (col ^ ((row & 7) << 4))] = f2bu((acc[i][j][r] + bv) * sc);
          }
        }
      }
      __syncthreads();
      for (int k = 0; k < TM * TN / 8 / 256; ++k) {
        int ch = tid + k * 256;
        int row = ch >> 4, col0 = (ch & 15) * 8;
        u16x8 v8 = *(const u16x8*)(Ls + (size_t)row * TN + (col0 ^ ((row & 7) << 4)));
        int m = m0 + row;
        int b = m >> 11, s = m & 2047;
        int n = n0 + col0;
        int h = (n & 1023) >> 6, d0 = n & 63;
        // 8 consecutive lanes cover one full 128B row [b,h,s,0..63]
        *(u16x8*)(Od + (((size_t)(b * 16 + h)) * 2048 + s) * 64 + d0) = v8;
      }
    } else {
      // ---- V tile: in-register permlane transpose -> u16x8 stores (8 consec s) ----
      for (int j = 0; j < NJ; ++j) {
        int n = n0 + wc * (TN / 2) + j * 16 + l16;
        int h = (n & 1023) >> 6, d = n & 63;
        float bv = bias[n];
        for (int pr = 0; pr < NI / 2; ++pr) {
          const f32x4& e = acc[2 * pr][j];
          const f32x4& f = acc[2 * pr + 1][j];
          bf16x2 e01 = {(__bf16)(e[0] + bv), (__bf16)(e[1] + bv)};
          bf16x2 e23 = {(__bf16)(e[2] + bv), (__bf16)(e[3] + bv)};
          bf16x2 f01 = {(__bf16)(f[0] + bv), (__bf16)(f[1] + bv)};
          bf16x2 f23 = {(__bf16)(f[2] + bv), (__bf16)(f[3] + bv)};
          u32 E[2] = {__builtin_bit_cast(u32, e01), __builtin_bit_cast(u32, e23)};
          u32 F[2] = {__builtin_bit_cast(u32, f01), __builtin_bit_cast(u32, f23)};
          u32 G[2], H[2];
          for (int w2 = 0; w2 < 2; ++w2) {
            u32x2 s1 = __builtin_amdgcn_permlane32_swap(E[w2], F[w2], false, false);
            u32x2 s2 = __builtin_amdgcn_permlane16_swap(s1[0], s1[1], false, false);
            G[w2] = s2[0];
            H[w2] = s2[1];
          }
          u32x4 pk = {G[0], G[1], H[0], H[1]};  // 8 consecutive m for this lane's col
          int m = m0 + wr * (TM / 2) + pr * 32 + quad * 8;
          int b = m >> 11, s = m & 2047;
          *(u32x4*)(O2 + (((size_t)(b * 16 + h)) * 64 + d) * 2048 + s) = pk;
        }
      }
    }
  }
}

// ---------------- flash attention: 4-way split-KV, 1024 threads, 8 waves/SIMD -------
// R10: R9's structure was CORRECT on HW (absmax passed) but __launch_bounds__
// (1024, 8) made the compiler cap VGPR at 32 -> total spill (FETCH 495MB, WRITE
// 964MB scratch, 302us). Fix: (1024, 4) -> VGPR cap 128, natural allocation
// expected ~48-56 (R8's near-identical, slightly LARGER state compiled to 52).
// If natural VGPR <= 64, the 64KB LDS allows 2 blocks/CU = 32 waves/CU = 8
// waves/SIMD (the occupancy doubling: R5's 2->4 gave -8.1us on this latency-
// bound kernel). Failure signature: VGPR>=65 -> 1 block/CU -> dur ~43+.
__global__ __launch_bounds__(1024, 4) void flash_attn(const u16* __restrict__ Q,
                                                      const u16* __restrict__ K,
                                                      const u16* __restrict__ Vt,
                                                      u16* __restrict__ AO) {
  constexpr int S = 2048;
  constexpr int QTR = S / 4;      // 512 kv per group
  constexpr int KVB = 32;         // t-tile per iter
  constexpr int NIT = QTR / KVB;  // 16
  __shared__ __bf16 lds[4][2][2][KVB * 64];  // [grp][K|V][dbuf][2048] = 64KB

  int bh = blockIdx.x, qbase = blockIdx.y * 128;
  int tid = threadIdx.x;
  int grp = tid >> 8, gtid = tid & 255;
  int w = gtid >> 6, lane = tid & 63, quad = lane >> 4, l16 = lane & 15;

  const u16* Qh = Q + (size_t)bh * S * 64;
  const u16* Kh = K + (size_t)bh * S * 64 + (size_t)grp * QTR * 64;
  const u16* Vh = Vt + (size_t)bh * 64 * S + grp * QTR;  // Vt[d][s], col offset

  // two q-row groups per wave: A = w*32 + l16, B = A + 16 (same rows in all grps)
  int qrowA = qbase + w * 32 + l16;
  int qrowB = qrowA + 16;
  bf16x8 qf0a = *(const bf16x8*)(Qh + (size_t)qrowA * 64 + quad * 8);
  bf16x8 qf1a = *(const bf16x8*)(Qh + (size_t)qrowA * 64 + 32 + quad * 8);
  bf16x8 qf0b = *(const bf16x8*)(Qh + (size_t)qrowB * 64 + quad * 8);
  bf16x8 qf1b = *(const bf16x8*)(Qh + (size_t)qrowB * 64 + 32 + quad * 8);

  bf16x8 vone;
#pragma unroll
  for (int j = 0; j < 8; ++j) vone[j] = (__bf16)1.0f;

  // staging: 2 gld16/thread/iter, pre-swizzled global source, linear LDS dest.
  // K: wave w stages t-rows [8w,8w+8) (rows of 64 bf16, 8 granules, XOR row&7).
  // V: wave w stages d-rows [16w,16w+16) (rows of 32 bf16, 4 granules, XOR (row>>1)&3).
  int lrK = lane >> 3;
  const u16* Ksrc = Kh + ((size_t)(w * 8 + lrK)) * 64 + (((lane & 7) ^ lrK) << 3);
  int lrV = lane >> 2;
  const u16* Vsrc = Vh + ((size_t)(w * 16 + lrV)) * S + (((lane & 3) ^ ((lane >> 3) & 3)) << 3);
  const __bf16* Kdst = &lds[grp][0][0][0] + w * 512;
  const __bf16* Vdst = &lds[grp][1][0][0] + w * 512;

#define STAGE(c, tb)                                     \
  {                                                      \
    gld16(Ksrc + (size_t)(tb) * 64, Kdst + (c) * 2048);  \
    gld16(Vsrc + (tb), Vdst + (c) * 2048);               \
  }

  STAGE(0, 0);
  __syncthreads();

  f32x4 oA[4] = {};
  f32x4 oB[4] = {};
  f32x4 lfA = {};
  f32x4 lfB = {};
  int xr = l16 & 7;
  int xv = (l16 >> 1) & 3;
  const __bf16* Kb0 = &lds[grp][0][0][0];
  const __bf16* Vb0 = &lds[grp][1][0][0];

  for (int it = 0; it < NIT; ++it) {
    int c = it & 1;
    if (it + 1 < NIT) STAGE(1 - c, (it + 1) * KVB);

    // QK^T + exp2, packed into u32 words (compiler fuses to v_cvt_pk_bf16_f32)
    u32 pwA[2][2], pwB[2][2];
#pragma unroll
    for (int nt = 0; nt < 2; ++nt) {
      const __bf16* kb = Kb0 + c * 2048 + (nt * 16 + l16) * 64;
      bf16x8 kf0 = *(const bf16x8*)(kb + ((quad ^ xr) << 3));
      bf16x8 kf1 = *(const bf16x8*)(kb + (((quad + 4) ^ xr) << 3));
      f32x4 ca = {0.f, 0.f, 0.f, 0.f};
      f32x4 cb = {0.f, 0.f, 0.f, 0.f};
      __builtin_amdgcn_s_setprio(1);
      ca = __builtin_amdgcn_mfma_f32_16x16x32_bf16(kf0, qf0a, ca, 0, 0, 0);
      cb = __builtin_amdgcn_mfma_f32_16x16x32_bf16(kf0, qf0b, cb, 0, 0, 0);
      ca = __builtin_amdgcn_mfma_f32_16x16x32_bf16(kf1, qf1a, ca, 0, 0, 0);
      cb = __builtin_amdgcn_mfma_f32_16x16x32_bf16(kf1, qf1b, cb, 0, 0, 0);
      __builtin_amdgcn_s_setprio(0);
      bf16x2 a01 = {(__bf16)__builtin_amdgcn_exp2f(ca[0]), (__bf16)__builtin_amdgcn_exp2f(ca[1])};
      bf16x2 a23 = {(__bf16)__builtin_amdgcn_exp2f(ca[2]), (__bf16)__builtin_amdgcn_exp2f(ca[3])};
      bf16x2 b01 = {(__bf16)__builtin_amdgcn_exp2f(cb[0]), (__bf16)__builtin_amdgcn_exp2f(cb[1])};
      bf16x2 b23 = {(__bf16)__builtin_amdgcn_exp2f(cb[2]), (__bf16)__builtin_amdgcn_exp2f(cb[3])};
      pwA[nt][0] = __builtin_bit_cast(u32, a01);
      pwA[nt][1] = __builtin_bit_cast(u32, a23);
      pwB[nt][0] = __builtin_bit_cast(u32, b01);
      pwB[nt][1] = __builtin_bit_cast(u32, b23);
    }

    // register-only redistribution (single stage: nt0/nt1 -> pf covering t0..31)
    bf16x8 pfA, pfB;
    {
      u32 GA[2], HA[2], GB[2], HB[2];
#pragma unroll
      for (int w2 = 0; w2 < 2; ++w2) {
        u32x2 s1a = __builtin_amdgcn_permlane32_swap(pwA[0][w2], pwA[1][w2], false, false);
        u32x2 s2a = __builtin_amdgcn_permlane16_swap(s1a[0], s1a[1], false, false);
        GA[w2] = s2a[0];
        HA[w2] = s2a[1];
        u32x2 s1b = __builtin_amdgcn_permlane32_swap(pwB[0][w2], pwB[1][w2], false, false);
        u32x2 s2b = __builtin_amdgcn_permlane16_swap(s1b[0], s1b[1], false, false);
        GB[w2] = s2b[0];
        HB[w2] = s2b[1];
      }
      u32x4 pa = {GA[0], GA[1], HA[0], HA[1]};
      u32x4 pb = {GB[0], GB[1], HB[0], HB[1]};
      pfA = __builtin_bit_cast(bf16x8, pa);
      pfB = __builtin_bit_cast(bf16x8, pb);
    }

    // l = row-sums of P via matrix pipe (B = ones); C-layout row matches o's row.
    __builtin_amdgcn_s_setprio(1);
    lfA = __builtin_amdgcn_mfma_f32_16x16x32_bf16(pfA, vone, lfA, 0, 0, 0);
    lfB = __builtin_amdgcn_mfma_f32_16x16x32_bf16(pfB, vone, lfB, 0, 0, 0);
    __builtin_amdgcn_s_setprio(0);

#pragma unroll
    for (int dt = 0; dt < 4; ++dt) {
      const __bf16* vb = Vb0 + c * 2048 + (dt * 16 + l16) * 32;
      bf16x8 v0 = *(const bf16x8*)(vb + ((quad ^ xv) << 3));
      __builtin_amdgcn_s_setprio(1);
      oA[dt] = __builtin_amdgcn_mfma_f32_16x16x32_bf16(pfA, v0, oA[dt], 0, 0, 0);
      oB[dt] = __builtin_amdgcn_mfma_f32_16x16x32_bf16(pfB, v0, oB[dt], 0, 0, 0);
      __builtin_amdgcn_s_setprio(0);
    }
    __syncthreads();  // drains this iter's STAGE loads; all groups same iter count
  }
#undef STAGE

  // ---- 4-way split-KV merge through dead LDS. Odd strides (21/41 f32) -> no
  // bank conflicts. Phase 1/2: grp1->grp0, grp3->grp2 (oA+lfA, then oB+lfB).
  // Phase 3: grp2->grp0 (all 40). grp0 normalizes and writes.
  float* mf = (float*)&lds[0][0][0][0];
  if (grp & 1) {
    float* p = mf + (size_t)((grp >> 1) * 256 + gtid) * 21;
#pragma unroll
    for (int dt = 0; dt < 4; ++dt)
#pragma unroll
      for (int r = 0; r < 4; ++r) p[dt * 4 + r] = oA[dt][r];
#pragma unroll
    for (int r = 0; r < 4; ++r) p[16 + r] = lfA[r];
  }
  __syncthreads();
  if (!(grp & 1)) {
    const float* p = mf + (size_t)((grp >> 1) * 256 + gtid) * 21;
#pragma unroll
    for (int dt = 0; dt < 4; ++dt)
#pragma unroll
      for (int r = 0; r < 4; ++r) oA[dt][r] += p[dt * 4 + r];
#pragma unroll
    for (int r = 0; r < 4; ++r) lfA[r] += p[16 + r];
  }
  __syncthreads();
  if (grp & 1) {
    float* p = mf + (size_t)((grp >> 1) * 256 + gtid) * 21;
#pragma unroll
    for (int dt = 0; dt < 4; ++dt)
#pragma unroll
      for (int r = 0; r < 4; ++r) p[dt * 4 + r] = oB[dt][r];
#pragma unroll
    for (int r = 0; r < 4; ++r) p[16 + r] = lfB[r];
  }
  __syncthreads();
  if (!(grp & 1)) {
    const float* p = mf + (size_t)((grp >> 1) * 256 + gtid) * 21;
#pragma unroll
    for (int dt = 0; dt < 4; ++dt)
#pragma unroll
      for (int r = 0; r < 4; ++r) oB[dt][r] += p[dt * 4 + r];
#pragma unroll
    for (int r = 0; r < 4; ++r) lfB[r] += p[16 + r];
  }
  __syncthreads();
  if (grp == 2) {
    float* p = mf + (size_t)gtid * 41;
#pragma unroll
    for (int dt = 0; dt < 4; ++dt)
#pragma unroll
      for (int r = 0; r < 4; ++r) {
        p[dt * 4 + r] = oA[dt][r];
        p[16 + dt * 4 + r] = oB[dt][r];
      }
#pragma unroll
    for (int r = 0; r < 4; ++r) {
      p[32 + r] = lfA[r];
      p[36 + r] = lfB[r];
    }
  }
  __syncthreads();
  if (grp == 0) {
    const float* p = mf + (size_t)gtid * 41;
    float linvA[4], linvB[4];
#pragma unroll
    for (int r = 0; r < 4; ++r) {
      linvA[r] = 1.f / (lfA[r] + p[32 + r]);
      linvB[r] = 1.f / (lfB[r] + p[36 + r]);
    }
    int b = bh >> 4, h = bh & 15;
    for (int dt = 0; dt < 4; ++dt)
      for (int r = 0; r < 4; ++r) {
        int sA = qbase + w * 32 + quad * 4 + r;
        int sB = sA + 16;
        int d = dt * 16 + l16;
        AO[(((size_t)b * 2048 + sA) * 16 + h) * 64 + d] = f2bu((oA[dt][r] + p[dt * 4 + r]) * linvA[r]);
        AO[(((size_t)b * 2048 + sB) * 16 + h) * 64 + d] = f2bu((oB[dt][r] + p[16 + dt * 4 + r]) * linvB[r]);
      }
  }
}

// ---------------- launch ----------------
extern "C" void kernel_launch(void* const* d_in, const int* in_sizes, int n_in,
                              void* d_out, int out_size, void* d_ws, size_t ws_size,
                              hipStream_t stream) {
  const float* x    = (const float*)d_in[0];  // [4096,1024] f32
  const float* Wqkv = (const float*)d_in[1];  // [1024,3072] f32
  const float* bqkv = (const float*)d_in[2];  // [3072] f32
  const float* Wout = (const float*)d_in[3];  // [1024,1024] f32
  const float* bout = (const float*)d_in[4];  // [1024] f32
  float* out = (float*)d_out;                 // [4096,1024] f32

  u16* ws = (u16*)d_ws;
  size_t off = 0;
  u16* Wqkv_t = ws + off; off += (size_t)3072 * 1024;
  u16* Wout_t = ws + off; off += (size_t)1024 * 1024;
  u16* xb     = ws + off; off += (size_t)4096 * 1024;  // AO aliases xb (dead after gemm1)
  u16* Qb     = ws + off; off += (size_t)32 * 2048 * 64;
  u16* Kb     = ws + off; off += (size_t)32 * 2048 * 64;
  u16* Vtb    = ws + off; off += (size_t)32 * 2048 * 64;  // written TRANSPOSED by gemm1
  u16* AO     = xb;
  // total: ~42 MB

  prep<<<dim3(3072), 256, 0, stream>>>(Wqkv, Wqkv_t, Wout, Wout_t, x, xb);
  // gemm1: 32 m-tiles x 24 n-tiles (TM=TN=128); XCD region 8m x 12n (A 2MB + Bt 3MB / L2)
  gemm_bt<1, 128, 128, 32, 24, 8, 12><<<dim3(768), 256, 0, stream>>>(
      xb, Wqkv_t, bqkv, (void*)Qb, Kb, Vtb, 4096, 3072, 1024);
  // flash: 128 q-rows per block, 1024 threads (4 KV-quarter groups x 4 waves);
  // blockIdx.x fastest -> all q-blocks of head bh land on XCD bh%8 (4 heads x
  // 512KB K+V = 2MB per L2). 512 blocks; 2/CU if VGPR<=64 -> 8 waves/SIMD.
  flash_attn<<<dim3(32, 16), 1024, 0, stream>>>(Qb, Kb, Vtb, AO);
  // gemm2: 32 m-tiles x 16 n-tiles (TM=128, TN=64); XCD region 8m x 8n (A 2MB + Bt 1MB / L2)
  gemm_bt<0, 128, 64, 32, 16, 8, 8><<<dim3(512), 256, 0, stream>>>(
      AO, Wout_t, bout, (void*)out, nullptr, nullptr, 4096, 1024, 1024);
}

// Round 11
// 175.667 us; speedup vs baseline: 2.4899x; 1.0178x over previous
//
#include <hip/hip_runtime.h>

typedef __bf16 bf16x8 __attribute__((ext_vector_type(8)));
typedef __bf16 bf16x4 __attribute__((ext_vector_type(4)));
typedef __bf16 bf16x2 __attribute__((ext_vector_type(2)));
typedef float f32x4 __attribute__((ext_vector_type(4)));
typedef unsigned short u16;
typedef unsigned short u16x4 __attribute__((ext_vector_type(4)));
typedef unsigned short u16x8 __attribute__((ext_vector_type(8)));
typedef unsigned int u32;
typedef unsigned int u32x2 __attribute__((ext_vector_type(2)));
typedef unsigned int u32x4 __attribute__((ext_vector_type(4)));

__device__ __forceinline__ u16 f2bu(float f) {
  __bf16 h = (__bf16)f;
  return __builtin_bit_cast(u16, h);
}

// async global->LDS, 16B/lane. LDS dest = wave-uniform base + lane*16.
__device__ __forceinline__ void gld16(const u16* g, const __bf16* lds) {
  __builtin_amdgcn_global_load_lds(
      (const __attribute__((address_space(1))) u32*)(uintptr_t)g,
      (__attribute__((address_space(3))) u32*)(u32)(uintptr_t)lds, 16, 0, 0);
}

// ---------------- transpose tile helper: out_bf16[C][R] tile from in_f32[R][C] -------
__device__ __forceinline__ void tr_tile(const float* __restrict__ in, u16* __restrict__ out,
                                        int R, int C, int bx, int by, int tid) {
  __shared__ u16 t[64][65];
  int tx = tid & 63, ty = tid >> 6;
  int r0 = by * 64, c0 = bx * 64;
  for (int i = 0; i < 16; ++i)
    t[ty + i * 4][tx] = f2bu(in[(size_t)(r0 + ty + i * 4) * C + c0 + tx]);
  __syncthreads();
  for (int i = 0; i < 16; ++i)
    out[(size_t)(c0 + ty + i * 4) * R + r0 + tx] = t[tx][ty + i * 4];
}

// ---------------- fused prep: tr(Wqkv) [0,768) | tr(Wout) [768,1024) | cvt(x) [1024,3072)
__global__ __launch_bounds__(256) void prep(const float* __restrict__ Wqkv,
                                            u16* __restrict__ Wqkv_t,
                                            const float* __restrict__ Wout,
                                            u16* __restrict__ Wout_t,
                                            const float* __restrict__ x,
                                            u16* __restrict__ xb) {
  int id = blockIdx.x, tid = threadIdx.x;
  if (id < 768) {
    tr_tile(Wqkv, Wqkv_t, 1024, 3072, id % 48, id / 48, tid);
  } else if (id < 1024) {
    int id2 = id - 768;
    tr_tile(Wout, Wout_t, 1024, 1024, id2 % 16, id2 / 16, tid);
  } else {
    size_t i = ((size_t)(id - 1024) * 256 + tid) * 8;
    f32x4 a0 = *(const f32x4*)(x + i);
    f32x4 a1 = *(const f32x4*)(x + i + 4);
    bf16x8 v;
    for (int j = 0; j < 4; ++j) { v[j] = (__bf16)a0[j]; v[j + 4] = (__bf16)a1[j]; }
    *(bf16x8*)(xb + i) = v;
  }
}

// ---------------- GEMM: dbuf K-loop, ONE barrier per 32-k step, XCD-swizzled --------
// MODE 0: C f32 -> O0.
// MODE 1: qkv scatter. Q(O0) scaled by 0.125*log2(e), [b,h,s,d]. K(O1) [b,h,s,d].
// V(O2) TRANSPOSED [b,h,d,s]. Epilogues coalesced via LDS restage (Q/K) and
// in-register permlane transpose (V).
template <int MODE, int TM, int TN, int MT, int NT, int XM, int XN>
__global__ __launch_bounds__(256) void gemm_bt(const u16* __restrict__ A,
                                               const u16* __restrict__ Bt,
                                               const float* __restrict__ bias,
                                               void* __restrict__ O0v,
                                               u16* __restrict__ O1,
                                               u16* __restrict__ O2,
                                               int M, int N, int K) {
  constexpr int NI = TM / 32;
  constexpr int NJ = TN / 32;
  constexpr int AE = TM * 32;
  constexpr int BE = TN * 32;
  __shared__ __bf16 smem[2 * (AE + BE)];

  int tid = threadIdx.x;
  int w = tid >> 6, lane = tid & 63, quad = lane >> 4, l16 = lane & 15;
  int wr = w >> 1, wc = w & 1;

  // XCD swizzle: xcd = id%8 owns tiles [mg*XM, mg*XM+XM) x [ng*XN, ng*XN+XN)
  int id = blockIdx.x;
  int xcd = id & 7, s0i = id >> 3;
  int mg = xcd % (MT / XM), ng = xcd / (MT / XM);
  int sm = s0i % XM, sn = s0i / XM;
  int m0 = (mg * XM + sm) * TM, n0 = (ng * XN + sn) * TN;

  int srow = w * 16 + (lane >> 2);
  int sch = (lane & 3) ^ ((lane >> 3) & 3);
  const u16* Ag = A + (size_t)(m0 + srow) * K + sch * 8;
  const u16* Bg = Bt + (size_t)(n0 + srow) * K + sch * 8;

  int swl = (quad ^ ((l16 >> 1) & 3)) << 3;

  f32x4 acc[NI][NJ] = {};

#define GLD_STEP(c, kk)                                                          \
  {                                                                              \
    for (int p = 0; p < TM / 64; ++p)                                            \
      gld16(Ag + (size_t)p * 64 * K + (kk), smem + (c) * (AE + BE) + w * 512 + p * 2048); \
    for (int p = 0; p < TN / 64; ++p)                                            \
      gld16(Bg + (size_t)p * 64 * K + (kk), smem + (c) * (AE + BE) + AE + w * 512 + p * 2048); \
  }

  GLD_STEP(0, 0);
  int NS = K / 32;
  for (int s = 0; s < NS; ++s) {
    int cur = s & 1;
    __syncthreads();  // drains step-s loads (issued one compute-phase ago)
    if (s + 1 < NS) GLD_STEP(1 - cur, (s + 1) * 32);
    const __bf16* Asub = smem + cur * (AE + BE);
    const __bf16* Bsub = Asub + AE;
    bf16x8 af[NI], bfr[NJ];
    for (int i = 0; i < NI; ++i)
      af[i] = *(const bf16x8*)(Asub + (wr * (TM / 2) + i * 16 + l16) * 32 + swl);
    for (int j = 0; j < NJ; ++j)
      bfr[j] = *(const bf16x8*)(Bsub + (wc * (TN / 2) + j * 16 + l16) * 32 + swl);
    for (int i = 0; i < NI; ++i)
      for (int j = 0; j < NJ; ++j)
        acc[i][j] = __builtin_amdgcn_mfma_f32_16x16x32_bf16(af[i], bfr[j], acc[i][j], 0, 0, 0);
  }
#undef GLD_STEP

  if (MODE == 0) {
    float* O0 = (float*)O0v;
    for (int j = 0; j < NJ; ++j) {
      int n = n0 + wc * (TN / 2) + j * 16 + l16;
      float bv = bias[n];
      for (int i = 0; i < NI; ++i) {
        int mb = m0 + wr * (TM / 2) + i * 16 + quad * 4;
        for (int r = 0; r < 4; ++r)
          O0[(size_t)(mb + r) * N + n] = acc[i][j][r] + bv;
      }
    }
  } else {
    constexpr float QSC = 0.125f * 1.44269504f;  // softmax scale * log2(e) folded into Q
    int bw = n0 >> 10;  // block-uniform: TN=128 divides 1024
    if (bw < 2) {
      // ---- Q/K tile: LDS restage -> fully coalesced 128B head-row stores ----
      u16* Od = bw ? O1 : (u16*)O0v;
      float sc = bw ? 1.f : QSC;
      __syncthreads();  // staging smem dead after final K-step reads
      u16* Ls = (u16*)smem;  // logical [row 0..TM) x [col 0..TN), granule-XOR'd
      for (int j = 0; j < NJ; ++j) {
        int col = wc * (TN / 2) + j * 16 + l16;
        float bv = bias[n0 + col];
        for (int i = 0; i < NI; ++i) {
          int rowb = wr * (TM / 2) + i * 16 + quad * 4;
          for (int r = 0; r < 4; ++r) {
            int row = rowb + r;
            Ls[(size_t)row * TN + (col ^ ((row & 7) << 4))] = f2bu((acc[i][j][r] + bv) * sc);
          }
        }
      }
      __syncthreads();
      for (int k = 0; k < TM * TN / 8 / 256; ++k) {
        int ch = tid + k * 256;
        int row = ch >> 4, col0 = (ch & 15) * 8;
        u16x8 v8 = *(const u16x8*)(Ls + (size_t)row * TN + (col0 ^ ((row & 7) << 4)));
        int m = m0 + row;
        int b = m >> 11, s = m & 2047;
        int n = n0 + col0;
        int h = (n & 1023) >> 6, d0 = n & 63;
        // 8 consecutive lanes cover one full 128B row [b,h,s,0..63]
        *(u16x8*)(Od + (((size_t)(b * 16 + h)) * 2048 + s) * 64 + d0) = v8;
      }
    } else {
      // ---- V tile: in-register permlane transpose -> u16x8 stores (8 consec s) ----
      for (int j = 0; j < NJ; ++j) {
        int n = n0 + wc * (TN / 2) + j * 16 + l16;
        int h = (n & 1023) >> 6, d = n & 63;
        float bv = bias[n];
        for (int pr = 0; pr < NI / 2; ++pr) {
          const f32x4& e = acc[2 * pr][j];
          const f32x4& f = acc[2 * pr + 1][j];
          bf16x2 e01 = {(__bf16)(e[0] + bv), (__bf16)(e[1] + bv)};
          bf16x2 e23 = {(__bf16)(e[2] + bv), (__bf16)(e[3] + bv)};
          bf16x2 f01 = {(__bf16)(f[0] + bv), (__bf16)(f[1] + bv)};
          bf16x2 f23 = {(__bf16)(f[2] + bv), (__bf16)(f[3] + bv)};
          u32 E[2] = {__builtin_bit_cast(u32, e01), __builtin_bit_cast(u32, e23)};
          u32 F[2] = {__builtin_bit_cast(u32, f01), __builtin_bit_cast(u32, f23)};
          u32 G[2], H[2];
          for (int w2 = 0; w2 < 2; ++w2) {
            u32x2 s1 = __builtin_amdgcn_permlane32_swap(E[w2], F[w2], false, false);
            u32x2 s2 = __builtin_amdgcn_permlane16_swap(s1[0], s1[1], false, false);
            G[w2] = s2[0];
            H[w2] = s2[1];
          }
          u32x4 pk = {G[0], G[1], H[0], H[1]};  // 8 consecutive m for this lane's col
          int m = m0 + wr * (TM / 2) + pr * 32 + quad * 8;
          int b = m >> 11, s = m & 2047;
          *(u32x4*)(O2 + (((size_t)(b * 16 + h)) * 64 + d) * 2048 + s) = pk;
        }
      }
    }
  }
}

// ---------------- flash attention (split-KV 8-wave + gld16 staging + setprio) -------
// R11: exact restore of the R8 champion (measured 42.7us, VGPR 52). The occupancy
// ladder is closed: 2->4 waves/SIMD = -8.1us (R5), 4->8 = +5.5us (R10: more waves
// raised neither pipe; barrier lockstep + halved per-iter compute dominate). Four
// waves/SIMD with KVB=64 is this kernel's optimum; MFMA~43% + VALU~45% both
// half-loaded and overlapped, residual = barrier drain + LDS latency.
__global__ __launch_bounds__(512, 4) void flash_attn(const u16* __restrict__ Q,
                                                     const u16* __restrict__ K,
                                                     const u16* __restrict__ Vt,
                                                     u16* __restrict__ AO) {
  constexpr int S = 2048;
  constexpr int HALF = S / 2;
  constexpr int NIT = HALF / 64;  // 16
  // [group][K=0/V=1][dbuf][64*64] bf16 = 64KB; reused as f32 merge area at the end
  __shared__ __bf16 lds[2][2][2][64 * 64];

  int bh = blockIdx.x, qbase = blockIdx.y * 128;
  int tid = threadIdx.x;
  int grp = tid >> 8, gtid = tid & 255;
  int w = gtid >> 6, lane = tid & 63, quad = lane >> 4, l16 = lane & 15;

  const u16* Qh = Q + (size_t)bh * S * 64;
  const u16* Kh = K + (size_t)bh * S * 64 + (size_t)grp * HALF * 64;
  const u16* Vh = Vt + (size_t)bh * 64 * S + grp * HALF;  // Vt[d][s], col offset

  // two q-row groups per wave: A = w*32 + l16, B = A + 16 (same rows in both grp)
  int qrowA = qbase + w * 32 + l16;
  int qrowB = qrowA + 16;
  bf16x8 qf0a = *(const bf16x8*)(Qh + (size_t)qrowA * 64 + quad * 8);
  bf16x8 qf1a = *(const bf16x8*)(Qh + (size_t)qrowA * 64 + 32 + quad * 8);
  bf16x8 qf0b = *(const bf16x8*)(Qh + (size_t)qrowB * 64 + quad * 8);
  bf16x8 qf1b = *(const bf16x8*)(Qh + (size_t)qrowB * 64 + 32 + quad * 8);

  bf16x8 vone;
#pragma unroll
  for (int j = 0; j < 8; ++j) vone[j] = (__bf16)1.0f;

  __bf16* Ks0 = &lds[grp][0][0][0];
  __bf16* Vs0 = &lds[grp][1][0][0];

  // pre-swizzled-source gld16 staging: wave w stages K rows / V d-rows [16w,16w+16)
  int lrow = lane >> 3, lgr = lane & 7;
  int sgr = (lgr ^ lrow) << 3;  // source granule (u16 offset); row&7 == lrow
  const u16* Ksrc = Kh + ((size_t)(w * 16) + lrow) * 64 + sgr;  // + (tb+8p)*64
  const u16* Vsrc = Vh + ((size_t)(w * 16) + lrow) * S + sgr;   // + 8p*S + tb
  const __bf16* Kdst = Ks0 + w * 16 * 64;                       // + c*4096 + p*512
  const __bf16* Vdst = Vs0 + w * 16 * 64;

#define STAGE(c, tb)                                                    \
  {                                                                     \
    gld16(Ksrc + (size_t)(tb) * 64, Kdst + (c) * 4096);                 \
    gld16(Ksrc + (size_t)((tb) + 8) * 64, Kdst + (c) * 4096 + 512);     \
    gld16(Vsrc + (tb), Vdst + (c) * 4096);                              \
    gld16(Vsrc + (size_t)8 * S + (tb), Vdst + (c) * 4096 + 512);        \
  }

  STAGE(0, 0);
  __syncthreads();

  f32x4 oA[4] = {};
  f32x4 oB[4] = {};
  f32x4 lfA = {};
  f32x4 lfB = {};
  int xr = l16 & 7;

  for (int it = 0; it < NIT; ++it) {
    int c = it & 1;
    if (it + 1 < NIT) STAGE(1 - c, (it + 1) * 64);

    // QK^T + exp2, packed per-nt into u32 words (compiler fuses to v_cvt_pk_bf16_f32)
    u32 pwA[4][2], pwB[4][2];
#pragma unroll
    for (int nt = 0; nt < 4; ++nt) {
      const __bf16* kb = Ks0 + c * 4096 + (nt * 16 + l16) * 64;
      bf16x8 kf0 = *(const bf16x8*)(kb + ((quad ^ xr) << 3));
      bf16x8 kf1 = *(const bf16x8*)(kb + (((quad + 4) ^ xr) << 3));
      f32x4 ca = {0.f, 0.f, 0.f, 0.f};
      f32x4 cb = {0.f, 0.f, 0.f, 0.f};
      __builtin_amdgcn_s_setprio(1);
      ca = __builtin_amdgcn_mfma_f32_16x16x32_bf16(kf0, qf0a, ca, 0, 0, 0);
      cb = __builtin_amdgcn_mfma_f32_16x16x32_bf16(kf0, qf0b, cb, 0, 0, 0);
      ca = __builtin_amdgcn_mfma_f32_16x16x32_bf16(kf1, qf1a, ca, 0, 0, 0);
      cb = __builtin_amdgcn_mfma_f32_16x16x32_bf16(kf1, qf1b, cb, 0, 0, 0);
      __builtin_amdgcn_s_setprio(0);
      bf16x2 a01 = {(__bf16)__builtin_amdgcn_exp2f(ca[0]), (__bf16)__builtin_amdgcn_exp2f(ca[1])};
      bf16x2 a23 = {(__bf16)__builtin_amdgcn_exp2f(ca[2]), (__bf16)__builtin_amdgcn_exp2f(ca[3])};
      bf16x2 b01 = {(__bf16)__builtin_amdgcn_exp2f(cb[0]), (__bf16)__builtin_amdgcn_exp2f(cb[1])};
      bf16x2 b23 = {(__bf16)__builtin_amdgcn_exp2f(cb[2]), (__bf16)__builtin_amdgcn_exp2f(cb[3])};
      pwA[nt][0] = __builtin_bit_cast(u32, a01);
      pwA[nt][1] = __builtin_bit_cast(u32, a23);
      pwB[nt][0] = __builtin_bit_cast(u32, b01);
      pwB[nt][1] = __builtin_bit_cast(u32, b23);
    }

    // register-only redistribution: (E,F) -> permlane32_swap -> permlane16_swap -> (G,H)
    bf16x8 pfA[2], pfB[2];
#pragma unroll
    for (int h = 0; h < 2; ++h) {
      u32 GA[2], HA[2], GB[2], HB[2];
#pragma unroll
      for (int w2 = 0; w2 < 2; ++w2) {
        u32x2 s1a = __builtin_amdgcn_permlane32_swap(pwA[2 * h][w2], pwA[2 * h + 1][w2], false, false);
        u32x2 s2a = __builtin_amdgcn_permlane16_swap(s1a[0], s1a[1], false, false);
        GA[w2] = s2a[0];
        HA[w2] = s2a[1];
        u32x2 s1b = __builtin_amdgcn_permlane32_swap(pwB[2 * h][w2], pwB[2 * h + 1][w2], false, false);
        u32x2 s2b = __builtin_amdgcn_permlane16_swap(s1b[0], s1b[1], false, false);
        GB[w2] = s2b[0];
        HB[w2] = s2b[1];
      }
      u32x4 pa = {GA[0], GA[1], HA[0], HA[1]};
      u32x4 pb = {GB[0], GB[1], HB[0], HB[1]};
      pfA[h] = __builtin_bit_cast(bf16x8, pa);
      pfB[h] = __builtin_bit_cast(bf16x8, pb);
    }

    // l = row-sums of P via matrix pipe (B = ones); C-layout row matches o's row.
    __builtin_amdgcn_s_setprio(1);
    lfA = __builtin_amdgcn_mfma_f32_16x16x32_bf16(pfA[0], vone, lfA, 0, 0, 0);
    lfA = __builtin_amdgcn_mfma_f32_16x16x32_bf16(pfA[1], vone, lfA, 0, 0, 0);
    lfB = __builtin_amdgcn_mfma_f32_16x16x32_bf16(pfB[0], vone, lfB, 0, 0, 0);
    lfB = __builtin_amdgcn_mfma_f32_16x16x32_bf16(pfB[1], vone, lfB, 0, 0, 0);
    __builtin_amdgcn_s_setprio(0);

#pragma unroll
    for (int dt = 0; dt < 4; ++dt) {
      const __bf16* vb = Vs0 + c * 4096 + (dt * 16 + l16) * 64;
      bf16x8 v0 = *(const bf16x8*)(vb + ((quad ^ xr) << 3));
      bf16x8 v1 = *(const bf16x8*)(vb + (((quad + 4) ^ xr) << 3));
      __builtin_amdgcn_s_setprio(1);
      oA[dt] = __builtin_amdgcn_mfma_f32_16x16x32_bf16(pfA[0], v0, oA[dt], 0, 0, 0);
      oB[dt] = __builtin_amdgcn_mfma_f32_16x16x32_bf16(pfB[0], v0, oB[dt], 0, 0, 0);
      oA[dt] = __builtin_amdgcn_mfma_f32_16x16x32_bf16(pfA[1], v1, oA[dt], 0, 0, 0);
      oB[dt] = __builtin_amdgcn_mfma_f32_16x16x32_bf16(pfB[1], v1, oB[dt], 0, 0, 0);
      __builtin_amdgcn_s_setprio(0);
    }
    __syncthreads();  // drains this iter's STAGE loads; readers of buf 1-c start next iter
  }
#undef STAGE

  // ---- split-KV merge through LDS (K/V buffers dead now). Stride 41 f32: 9 odd
  // -> bank-conflict-free across lanes. grp1 parks partials, grp0 merges+writes.
  float* mf = (float*)&lds[0][0][0][0];
  if (grp) {
    float* p = mf + (size_t)gtid * 41;
#pragma unroll
    for (int dt = 0; dt < 4; ++dt)
#pragma unroll
      for (int r = 0; r < 4; ++r) {
        p[dt * 4 + r] = oA[dt][r];
        p[16 + dt * 4 + r] = oB[dt][r];
      }
#pragma unroll
    for (int r = 0; r < 4; ++r) {
      p[32 + r] = lfA[r];
      p[36 + r] = lfB[r];
    }
  }
  __syncthreads();
  if (!grp) {
    const float* p = mf + (size_t)gtid * 41;
    float linvA[4], linvB[4];
#pragma unroll
    for (int r = 0; r < 4; ++r) {
      linvA[r] = 1.f / (lfA[r] + p[32 + r]);
      linvB[r] = 1.f / (lfB[r] + p[36 + r]);
    }
    int b = bh >> 4, h = bh & 15;
    for (int dt = 0; dt < 4; ++dt)
      for (int r = 0; r < 4; ++r) {
        int sA = qbase + w * 32 + quad * 4 + r;
        int sB = sA + 16;
        int d = dt * 16 + l16;
        AO[(((size_t)b * 2048 + sA) * 16 + h) * 64 + d] = f2bu((oA[dt][r] + p[dt * 4 + r]) * linvA[r]);
        AO[(((size_t)b * 2048 + sB) * 16 + h) * 64 + d] = f2bu((oB[dt][r] + p[16 + dt * 4 + r]) * linvB[r]);
      }
  }
}

// ---------------- launch ----------------
extern "C" void kernel_launch(void* const* d_in, const int* in_sizes, int n_in,
                              void* d_out, int out_size, void* d_ws, size_t ws_size,
                              hipStream_t stream) {
  const float* x    = (const float*)d_in[0];  // [4096,1024] f32
  const float* Wqkv = (const float*)d_in[1];  // [1024,3072] f32
  const float* bqkv = (const float*)d_in[2];  // [3072] f32
  const float* Wout = (const float*)d_in[3];  // [1024,1024] f32
  const float* bout = (const float*)d_in[4];  // [1024] f32
  float* out = (float*)d_out;                 // [4096,1024] f32

  u16* ws = (u16*)d_ws;
  size_t off = 0;
  u16* Wqkv_t = ws + off; off += (size_t)3072 * 1024;
  u16* Wout_t = ws + off; off += (size_t)1024 * 1024;
  u16* xb     = ws + off; off += (size_t)4096 * 1024;  // AO aliases xb (dead after gemm1)
  u16* Qb     = ws + off; off += (size_t)32 * 2048 * 64;
  u16* Kb     = ws + off; off += (size_t)32 * 2048 * 64;
  u16* Vtb    = ws + off; off += (size_t)32 * 2048 * 64;  // written TRANSPOSED by gemm1
  u16* AO     = xb;
  // total: ~42 MB

  prep<<<dim3(3072), 256, 0, stream>>>(Wqkv, Wqkv_t, Wout, Wout_t, x, xb);
  // gemm1: 32 m-tiles x 24 n-tiles (TM=TN=128); XCD region 8m x 12n (A 2MB + Bt 3MB / L2)
  gemm_bt<1, 128, 128, 32, 24, 8, 12><<<dim3(768), 256, 0, stream>>>(
      xb, Wqkv_t, bqkv, (void*)Qb, Kb, Vtb, 4096, 3072, 1024);
  // flash: 128 q-rows per block, 512 threads (2 KV-half groups x 4 waves);
  // blockIdx.x fastest -> all q-blocks of head bh land on XCD bh%8 (4 heads x
  // 512KB K+V = 2MB per L2)
  flash_attn<<<dim3(32, 16), 512, 0, stream>>>(Qb, Kb, Vtb, AO);
  // gemm2: 32 m-tiles x 16 n-tiles (TM=128, TN=64); XCD region 8m x 8n (A 2MB + Bt 1MB / L2)
  gemm_bt<0, 128, 64, 32, 16, 8, 8><<<dim3(512), 256, 0, stream>>>(
      AO, Wout_t, bout, (void*)out, nullptr, nullptr, 4096, 1024, 1024);
}